// Round 1
// baseline (92.961 us; speedup 1.0000x reference)
//
#include <hip/hip_runtime.h>

#define SAMPLES 32
#define ELEMS_PER_SAMPLE (256 * 64 * 64)              // 1048576
#define VEC4_PER_SAMPLE (ELEMS_PER_SAMPLE / 4)        // 262144
#define BLOCKS_PER_SAMPLE 64
#define THREADS 256
#define ITERS (VEC4_PER_SAMPLE / (BLOCKS_PER_SAMPLE * THREADS))  // 16

#define BETA 2.0f
#define EPS 1e-5f

__device__ __forceinline__ float wave_reduce_sum(float v) {
#pragma unroll
    for (int off = 32; off > 0; off >>= 1)
        v += __shfl_down(v, off, 64);
    return v;
}

// ---------------- Kernel 1: per-sample sum & sumsq of teacher ----------------
__global__ __launch_bounds__(THREADS) void kd_stats_kernel(
    const float4* __restrict__ t, float* __restrict__ ws) {
    const int s = blockIdx.x / BLOCKS_PER_SAMPLE;
    const int b = blockIdx.x % BLOCKS_PER_SAMPLE;
    const float4* base =
        t + (size_t)s * VEC4_PER_SAMPLE + (size_t)b * (THREADS * ITERS);

    float sum = 0.0f, sumsq = 0.0f;
#pragma unroll
    for (int i = 0; i < ITERS; ++i) {
        float4 v = base[i * THREADS + threadIdx.x];
        sum += v.x + v.y + v.z + v.w;
        sumsq += v.x * v.x + v.y * v.y + v.z * v.z + v.w * v.w;
    }

    const int lane = threadIdx.x & 63;
    const int wid = threadIdx.x >> 6;
    sum = wave_reduce_sum(sum);
    sumsq = wave_reduce_sum(sumsq);

    __shared__ float sm[2 * (THREADS / 64)];
    if (lane == 0) {
        sm[wid] = sum;
        sm[(THREADS / 64) + wid] = sumsq;
    }
    __syncthreads();
    if (threadIdx.x == 0) {
        float a = sm[0] + sm[1] + sm[2] + sm[3];
        float q = sm[4] + sm[5] + sm[6] + sm[7];
        atomicAdd(&ws[s], a);
        atomicAdd(&ws[SAMPLES + s], q);
    }
}

// ---------------- Kernel 2: normalize + smooth-L1 + global reduce ----------------
__global__ __launch_bounds__(THREADS) void kd_loss_kernel(
    const float4* __restrict__ t, const float4* __restrict__ st,
    const float* __restrict__ ws, float* __restrict__ out) {
    const int s = blockIdx.x / BLOCKS_PER_SAMPLE;
    const int b = blockIdx.x % BLOCKS_PER_SAMPLE;

    const float inv_n = 1.0f / (float)ELEMS_PER_SAMPLE;
    const float mean = ws[s] * inv_n;
    const float var = ws[SAMPLES + s] * inv_n - mean * mean;
    const float rstd = rsqrtf(var + EPS);

    const size_t off =
        (size_t)s * VEC4_PER_SAMPLE + (size_t)b * (THREADS * ITERS);
    const float4* tb = t + off;
    const float4* sb = st + off;

    float acc = 0.0f;
#pragma unroll
    for (int i = 0; i < ITERS; ++i) {
        float4 tv = tb[i * THREADS + threadIdx.x];
        float4 sv = sb[i * THREADS + threadIdx.x];

        float d0 = fabsf((tv.x - mean) * rstd - sv.x);
        float d1 = fabsf((tv.y - mean) * rstd - sv.y);
        float d2 = fabsf((tv.z - mean) * rstd - sv.z);
        float d3 = fabsf((tv.w - mean) * rstd - sv.w);

        acc += (d0 <= BETA) ? (0.25f * d0 * d0) : (d0 - 1.0f);
        acc += (d1 <= BETA) ? (0.25f * d1 * d1) : (d1 - 1.0f);
        acc += (d2 <= BETA) ? (0.25f * d2 * d2) : (d2 - 1.0f);
        acc += (d3 <= BETA) ? (0.25f * d3 * d3) : (d3 - 1.0f);
    }

    const int lane = threadIdx.x & 63;
    const int wid = threadIdx.x >> 6;
    acc = wave_reduce_sum(acc);

    __shared__ float sm[THREADS / 64];
    if (lane == 0) sm[wid] = acc;
    __syncthreads();
    if (threadIdx.x == 0) {
        float a = sm[0] + sm[1] + sm[2] + sm[3];
        atomicAdd(out, a * (1.0f / (float)SAMPLES));  // LOSS_WEIGHT = 1
    }
}

extern "C" void kernel_launch(void* const* d_in, const int* in_sizes, int n_in,
                              void* d_out, int out_size, void* d_ws,
                              size_t ws_size, hipStream_t stream) {
    const float* teacher = (const float*)d_in[0];
    const float* student = (const float*)d_in[1];
    float* out = (float*)d_out;
    float* ws = (float*)d_ws;

    // zero the stats accumulators and the output (harness poisons them)
    hipMemsetAsync(ws, 0, 2 * SAMPLES * sizeof(float), stream);
    hipMemsetAsync(out, 0, sizeof(float), stream);

    const int grid = SAMPLES * BLOCKS_PER_SAMPLE;  // 2048 blocks
    kd_stats_kernel<<<grid, THREADS, 0, stream>>>((const float4*)teacher, ws);
    kd_loss_kernel<<<grid, THREADS, 0, stream>>>(
        (const float4*)teacher, (const float4*)student, ws, out);
}

// Round 2
// 64.491 us; speedup vs baseline: 1.4415x; 1.4415x over previous
//
#include <hip/hip_runtime.h>

#define SAMPLES 32
#define ELEMS_PER_SAMPLE (256 * 64 * 64)              // 1048576
#define VEC4_PER_SAMPLE (ELEMS_PER_SAMPLE / 4)        // 262144
#define BLOCKS_PER_SAMPLE 64
#define THREADS 256
#define GRID (SAMPLES * BLOCKS_PER_SAMPLE)            // 2048
#define ITERS (VEC4_PER_SAMPLE / (BLOCKS_PER_SAMPLE * THREADS))  // 16

#define BETA 2.0f
#define EPS 1e-5f

__device__ __forceinline__ float wave_reduce_sum(float v) {
#pragma unroll
    for (int off = 32; off > 0; off >>= 1)
        v += __shfl_down(v, off, 64);
    return v;
}

// ws layout (floats):
//   [0 .. 2*GRID)        per-block (sum, sumsq) pairs from kernel 1
//   [2*GRID .. 3*GRID)   per-block loss partials from kernel 2
#define LPART_OFF (2 * GRID)

// ---------------- Kernel 1: per-block teacher partial sum/sumsq ----------------
__global__ __launch_bounds__(THREADS) void kd_stats_kernel(
    const float4* __restrict__ t, float* __restrict__ ws) {
    const float4* base = t + (size_t)blockIdx.x * (THREADS * ITERS);

    float sum = 0.0f, sumsq = 0.0f;
#pragma unroll
    for (int i = 0; i < ITERS; ++i) {
        float4 v = base[i * THREADS + threadIdx.x];
        sum += v.x + v.y + v.z + v.w;
        sumsq += v.x * v.x + v.y * v.y + v.z * v.z + v.w * v.w;
    }

    const int lane = threadIdx.x & 63;
    const int wid = threadIdx.x >> 6;
    sum = wave_reduce_sum(sum);
    sumsq = wave_reduce_sum(sumsq);

    __shared__ float sm[2 * (THREADS / 64)];
    if (lane == 0) {
        sm[wid] = sum;
        sm[(THREADS / 64) + wid] = sumsq;
    }
    __syncthreads();
    if (threadIdx.x == 0) {
        ws[2 * blockIdx.x]     = sm[0] + sm[1] + sm[2] + sm[3];
        ws[2 * blockIdx.x + 1] = sm[4] + sm[5] + sm[6] + sm[7];
    }
}

// ---------------- Kernel 2: stats from partials + smooth-L1, per-block partial ----------------
__global__ __launch_bounds__(THREADS) void kd_loss_kernel(
    const float4* __restrict__ t, const float4* __restrict__ st,
    const float* __restrict__ ws, float* __restrict__ lpart) {
    const int s = blockIdx.x / BLOCKS_PER_SAMPLE;
    const int lane = threadIdx.x & 63;
    const int wid = threadIdx.x >> 6;

    // Each wave redundantly reduces this sample's 64 partial pairs (L2-hot).
    float psum   = ws[2 * (s * BLOCKS_PER_SAMPLE + lane)];
    float psumsq = ws[2 * (s * BLOCKS_PER_SAMPLE + lane) + 1];
    psum = wave_reduce_sum(psum);
    psumsq = wave_reduce_sum(psumsq);
    psum = __shfl(psum, 0, 64);
    psumsq = __shfl(psumsq, 0, 64);

    const float inv_n = 1.0f / (float)ELEMS_PER_SAMPLE;
    const float mean = psum * inv_n;
    const float var = psumsq * inv_n - mean * mean;
    const float rstd = rsqrtf(var + EPS);

    const size_t off = (size_t)blockIdx.x * (THREADS * ITERS);
    const float4* tb = t + off;
    const float4* sb = st + off;

    float acc = 0.0f;
#pragma unroll
    for (int i = 0; i < ITERS; ++i) {
        float4 tv = tb[i * THREADS + threadIdx.x];
        float4 sv = sb[i * THREADS + threadIdx.x];

        float d0 = fabsf((tv.x - mean) * rstd - sv.x);
        float d1 = fabsf((tv.y - mean) * rstd - sv.y);
        float d2 = fabsf((tv.z - mean) * rstd - sv.z);
        float d3 = fabsf((tv.w - mean) * rstd - sv.w);

        acc += (d0 <= BETA) ? (0.25f * d0 * d0) : (d0 - 1.0f);
        acc += (d1 <= BETA) ? (0.25f * d1 * d1) : (d1 - 1.0f);
        acc += (d2 <= BETA) ? (0.25f * d2 * d2) : (d2 - 1.0f);
        acc += (d3 <= BETA) ? (0.25f * d3 * d3) : (d3 - 1.0f);
    }

    acc = wave_reduce_sum(acc);
    __shared__ float sm[THREADS / 64];
    if (lane == 0) sm[wid] = acc;
    __syncthreads();
    if (threadIdx.x == 0)
        lpart[blockIdx.x] = sm[0] + sm[1] + sm[2] + sm[3];
}

// ---------------- Kernel 3: final reduce of 2048 partials ----------------
__global__ __launch_bounds__(THREADS) void kd_final_kernel(
    const float* __restrict__ lpart, float* __restrict__ out) {
    float acc = 0.0f;
#pragma unroll
    for (int i = 0; i < GRID / THREADS; ++i)  // 8
        acc += lpart[i * THREADS + threadIdx.x];

    const int lane = threadIdx.x & 63;
    const int wid = threadIdx.x >> 6;
    acc = wave_reduce_sum(acc);
    __shared__ float sm[THREADS / 64];
    if (lane == 0) sm[wid] = acc;
    __syncthreads();
    if (threadIdx.x == 0)
        out[0] = (sm[0] + sm[1] + sm[2] + sm[3]) * (1.0f / (float)SAMPLES);
}

extern "C" void kernel_launch(void* const* d_in, const int* in_sizes, int n_in,
                              void* d_out, int out_size, void* d_ws,
                              size_t ws_size, hipStream_t stream) {
    const float* teacher = (const float*)d_in[0];
    const float* student = (const float*)d_in[1];
    float* out = (float*)d_out;
    float* ws = (float*)d_ws;

    kd_stats_kernel<<<GRID, THREADS, 0, stream>>>((const float4*)teacher, ws);
    kd_loss_kernel<<<GRID, THREADS, 0, stream>>>(
        (const float4*)teacher, (const float4*)student, ws, ws + LPART_OFF);
    kd_final_kernel<<<1, THREADS, 0, stream>>>(ws + LPART_OFF, out);
}